// Round 7
// baseline (313.334 us; speedup 1.0000x reference)
//
#include <hip/hip_runtime.h>

// CrossSymmetricModal: two cross-attention branches. B=16, C=256, L=1024.
// R15: rank-4 algebra (clinical is [B,1,L]) -- branch-a attention is a
// streaming VALU kernel; branch-b QK^T is rank-4; P_b materialized bf16,
// PV + o-convs run in the proven gemm_nt (glds16 double-buffered).
// R16: attn_mid re-gridded for occupancy (1280 blocks).
// R17: push rank-4 through the weights: A[l][j'] = window(l).E[:,j'] + e0,
// Y[m][j'] = window(m).F[:,j'] + f0 with E = a_qw^T-contract-a_kw (768x4),
// F = b_kw^T-contract-b_qw (768x4) computed from WEIGHTS ONLY inside prep.
// The 512-block Q_a|K_b GEMM and the mats kernel are deleted; replaced by
// matsAY: one streaming pass over imgT (grid 256, 4 thr/row, shfl reduce).
// 1/16 score scale folded into E/F/e0/f0.
// Output [16][512][1024] fp32.

typedef short bf16x8 __attribute__((ext_vector_type(8)));
typedef float f32x4 __attribute__((ext_vector_type(4)));

__device__ __forceinline__ unsigned short f2bf(float f) {
    union { float f; unsigned u; } v; v.f = f;
    unsigned r = v.u + 0x7fffu + ((v.u >> 16) & 1u);   // RNE
    return (unsigned short)(r >> 16);
}
__device__ __forceinline__ float bf2f(unsigned short h) {
    union { unsigned u; float f; } v; v.u = ((unsigned)h) << 16;
    return v.f;
}

// async global->LDS, 16B per lane; HW writes lane i at lds_base + i*16 (m97/m104)
__device__ __forceinline__ void glds16(const void* g, void* l) {
    __builtin_amdgcn_global_load_lds(
        (const __attribute__((address_space(1))) unsigned int*)g,
        (__attribute__((address_space(3))) unsigned int*)l, 16, 0, 0);
}

// ---------------------------------------------------------------------------
// NT GEMM: 2-op batched, compact 1-D grid, double-buffered glds staging,
// LDS-transpose epilogue with coalesced 16B stores.  Per-op K; optional
// epilogue row-scale (PV normalization) and BN partial-stats atomics.
// ---------------------------------------------------------------------------
#define TM 128
#define TN 128
#define BK 32

struct GOp {
    const unsigned short* A; const unsigned short* B; void* C;
    long sA, sB, sC;
    int lda, ldb, ldc, nxt, nyt, nz, K;
    const float* bias_row; const float* bias_col;
    const float* row_scale;           // scale C row (i0+row) by rs[bz*M + row]
    float* stats; int stat_base;      // stats!=null: atomicAdd sum/sumsq per row
};

__global__ __launch_bounds__(256)
void gemm_nt(GOp op0, GOp op1, int n0, float alpha)
{
    __shared__ __attribute__((aligned(16))) char sh[34816];
    unsigned short* shs = (unsigned short*)sh;
    int id = blockIdx.x;
    const bool brn = (id >= n0);
    const GOp op = brn ? op1 : op0;
    if (brn) id -= n0;
    const int bz = id % op.nz;          // XCD swizzle
    const int rem = id / op.nz;
    const int by = rem / op.nxt;
    const int bx = rem - by * op.nxt;

    const unsigned short* Ab = op.A + op.sA * bz;
    const unsigned short* Bb = op.B + op.sB * bz;
    const int lda = op.lda, ldb = op.ldb;
    const int i0 = by * TM;
    const int j0 = bx * TN;
    const int t = threadIdx.x;
    const int lane = t & 63;
    const int wave = t >> 6;
    const int wm = wave & 1, wn = wave >> 1;

    const int srow = wave * 16 + (lane >> 2);
    const int sc8 = (lane & 3) * 8;
    const unsigned short* gA0 = Ab + (long)(i0 + srow) * lda + sc8;
    const unsigned short* gA1 = gA0 + (long)64 * lda;
    const unsigned short* gB0 = Bb + (long)(j0 + srow) * ldb + sc8;
    const unsigned short* gB1 = gB0 + (long)64 * ldb;
    const int d0 = wave * 512;
    const int d1 = 2048 + wave * 512;

    f32x4 acc[4][4];
#pragma unroll
    for (int a_ = 0; a_ < 4; ++a_)
#pragma unroll
        for (int b_ = 0; b_ < 4; ++b_)
            acc[a_][b_] = (f32x4){0.f, 0.f, 0.f, 0.f};

    const int frow = lane & 15;
    const int fk = (lane >> 4) * 8;

    glds16(gA0, shs + d0);
    glds16(gA1, shs + d1);
    glds16(gB0, shs + 8192 + d0);
    glds16(gB1, shs + 8192 + d1);

    int cur = 0;
    for (int k0 = 0; k0 < op.K; k0 += BK) {
        __syncthreads();
        const int kn = k0 + BK;
        if (kn < op.K) {
            const int nb = cur ^ 1;
            glds16(gA0 + kn, shs + nb * 4096 + d0);
            glds16(gA1 + kn, shs + nb * 4096 + d1);
            glds16(gB0 + kn, shs + 8192 + nb * 4096 + d0);
            glds16(gB1 + kn, shs + 8192 + nb * 4096 + d1);
        }
        const unsigned short* la = shs + cur * 4096;
        const unsigned short* lb = shs + 8192 + cur * 4096;
        bf16x8 af[4], bfr[4];
#pragma unroll
        for (int mt = 0; mt < 4; ++mt)
            af[mt] = *(const bf16x8*)(&la[(wm * 64 + mt * 16 + frow) * BK + fk]);
#pragma unroll
        for (int nt = 0; nt < 4; ++nt)
            bfr[nt] = *(const bf16x8*)(&lb[(wn * 64 + nt * 16 + frow) * BK + fk]);
#pragma unroll
        for (int mt = 0; mt < 4; ++mt)
#pragma unroll
            for (int nt = 0; nt < 4; ++nt)
                acc[mt][nt] = __builtin_amdgcn_mfma_f32_16x16x32_bf16(af[mt], bfr[nt], acc[mt][nt], 0, 0, 0);
        cur ^= 1;
    }

    const int lr = (lane >> 4) * 4;   // C/D: row=(lane>>4)*4+reg, col=lane&15 (m89/m91)
    const int lc = lane & 15;
    __syncthreads();

    unsigned short* tile = shs;       // [128][136]
#pragma unroll
    for (int mt = 0; mt < 4; ++mt) {
#pragma unroll
        for (int nt = 0; nt < 4; ++nt) {
            const int col = wn * 64 + nt * 16 + lc;
            const float bc = op.bias_col ? op.bias_col[j0 + col] : 0.f;
#pragma unroll
            for (int r = 0; r < 4; ++r) {
                const int row = wm * 64 + mt * 16 + lr + r;
                const float brv = op.bias_row ? op.bias_row[i0 + row] : 0.f;
                const float rsv = op.row_scale
                    ? op.row_scale[(long)bz * (op.nyt * TM) + i0 + row] : 1.f;
                tile[row * 136 + col] = f2bf((acc[mt][nt][r] * alpha + brv + bc) * rsv);
            }
        }
    }
    __syncthreads();
    unsigned short* Cb = (unsigned short*)op.C + op.sC * bz;
#pragma unroll
    for (int p = 0; p < 8; ++p) {
        const int cid = p * 256 + t;
        const int row = cid >> 4;
        const int c8 = (cid & 15) * 8;
        const uint4 v = *(const uint4*)(tile + row * 136 + c8);
        *(uint4*)(Cb + (long)(i0 + row) * op.ldc + j0 + c8) = v;
    }
    if (op.stats) {
        // per-channel (row) partial sums of the bf16 tile; 2 threads/row
        const int row = t >> 1, half = t & 1;
        float s = 0.f, s2 = 0.f;
#pragma unroll
        for (int c = 0; c < 64; c += 8) {
            const bf16x8 v = *(const bf16x8*)(tile + row * 136 + half * 64 + c);
#pragma unroll
            for (int e = 0; e < 8; ++e) {
                const float f = bf2f((unsigned short)v[e]);
                s += f; s2 += f * f;
            }
        }
        s += __shfl_xor(s, 1);
        s2 += __shfl_xor(s2, 1);
        if (half == 0) {
            const int ch = op.stat_base + i0 + row;
            atomicAdd(&op.stats[ch], s);
            atomicAdd(&op.stats[512 + ch], s2);
        }
    }
}

// ---------------------------------------------------------------------------
// matsAY (R17): M4A[z][l] = window(l).E + e0, M4Y[z][l] = window(l).F + f0.
// window(l) = imgT padded rows l..l+2 (= original l-1,l,l+1), 768 bf16.
// Grid 256 = 16 z x 16 chunks of 64 rows; 4 threads/row (q = k-quarter),
// shfl_xor(1,2) reduce.  EF: [768][8] f32 (E|F), cst: e0[4]|f0[4].
// ---------------------------------------------------------------------------
__global__ __launch_bounds__(256)
void matsAY(const unsigned short* __restrict__ imgT,
            const float* __restrict__ EF, const float* __restrict__ cst,
            float* __restrict__ M4A, float* __restrict__ M4Y)
{
    const int bid = blockIdx.x;
    const int z = bid & 15, chk = bid >> 4;
    const int t = threadIdx.x;
    const int r = t >> 2, q = t & 3;
    const int l = chk * 64 + r;
    const unsigned short* w = imgT + ((long)z * 1026 + l) * 256 + q * 192;
    const float* ef = EF + q * 192 * 8;
    float a0 = 0.f, a1 = 0.f, a2 = 0.f, a3 = 0.f;
    float y0 = 0.f, y1 = 0.f, y2 = 0.f, y3 = 0.f;
#pragma unroll 4
    for (int kk = 0; kk < 192; kk += 8) {
        const bf16x8 x8 = *(const bf16x8*)(w + kk);
#pragma unroll
        for (int e = 0; e < 8; ++e) {
            const float xf = bf2f((unsigned short)x8[e]);
            const float4 E = *(const float4*)(ef + (kk + e) * 8);
            const float4 F = *(const float4*)(ef + (kk + e) * 8 + 4);
            a0 += xf * E.x; a1 += xf * E.y; a2 += xf * E.z; a3 += xf * E.w;
            y0 += xf * F.x; y1 += xf * F.y; y2 += xf * F.z; y3 += xf * F.w;
        }
    }
    a0 += __shfl_xor(a0, 1); a0 += __shfl_xor(a0, 2);
    a1 += __shfl_xor(a1, 1); a1 += __shfl_xor(a1, 2);
    a2 += __shfl_xor(a2, 1); a2 += __shfl_xor(a2, 2);
    a3 += __shfl_xor(a3, 1); a3 += __shfl_xor(a3, 2);
    y0 += __shfl_xor(y0, 1); y0 += __shfl_xor(y0, 2);
    y1 += __shfl_xor(y1, 1); y1 += __shfl_xor(y1, 2);
    y2 += __shfl_xor(y2, 1); y2 += __shfl_xor(y2, 2);
    y3 += __shfl_xor(y3, 1); y3 += __shfl_xor(y3, 2);
    if (q == 0) {
        const float4 e0 = *(const float4*)cst;
        const float4 f0 = *(const float4*)(cst + 4);
        const long o = ((long)z * 1024 + l) * 4;
        *(float4*)(M4A + o) = make_float4(a0 + e0.x, a1 + e0.y, a2 + e0.z, a3 + e0.w);
        *(float4*)(M4Y + o) = make_float4(y0 + f0.x, y1 + f0.y, y2 + f0.z, y3 + f0.w);
    }
}

// ---------------------------------------------------------------------------
// attn_mid, grid 1280 (R16):
//  bid<256: branch a. Block = (z = bid&15, 64-row chunk).  4 threads/row
//    stream 256 m each (xs in LDS), shfl_xor(1,2) reduce, t_hat to LDS;
//    epilogue: thread=channel writes ctx_a[c][l] for the 64 rows.
//  bid>=256: branch b. Block = (z, 16-row chunk), 16 threads/row.  NO LDS:
//    y as coalesced float4 from global (L1-resident), P direct bf16x8 to
//    global, rowsum via shfl_xor over mg=t&15, invl by mg==0.
//  (1/16 scale pre-folded into M4A/M4Y -- R17.)
// ---------------------------------------------------------------------------
__global__ __launch_bounds__(256)
void attn_mid(const float* __restrict__ cli,
              const float* __restrict__ M4A, const float* __restrict__ M4Y,
              const float* __restrict__ a_vw, const float* __restrict__ a_vb,
              unsigned short* __restrict__ P, float* __restrict__ invl,
              unsigned short* __restrict__ ctxT)
{
    __shared__ __attribute__((aligned(16))) float smem[1032 + 256];  // xs | tt
    const int bid = blockIdx.x;
    const int t = threadIdx.x;
    if (bid < 256) {
        // ---------------- branch a ----------------
        const int z = bid & 15;
        const int l0 = (bid >> 4) << 6;
        float* xs = smem;                               // [1026]
        float* tt = smem + 1032;                        // [64][4]
        for (int i = t; i < 1026; i += 256) {
            const int l = i - 1;
            xs[i] = (l >= 0 && l < 1024) ? cli[(long)z * 1024 + l] : 0.f;
        }
        __syncthreads();
        const int r = t >> 2, q = t & 3;
        const float4 A = *(const float4*)(M4A + ((long)z * 1024 + l0 + r) * 4);
        float t0 = 0.f, t1 = 0.f, t2 = 0.f, ls = 0.f;
        const int m0 = q * 256;
#pragma unroll 4
        for (int m = m0; m < m0 + 256; ++m) {
            const float x0 = xs[m], x1 = xs[m + 1], x2 = xs[m + 2];
            const float e = __expf(A.x * x0 + A.y * x1 + A.z * x2 + A.w);
            t0 += e * x0; t1 += e * x1; t2 += e * x2; ls += e;
        }
        t0 += __shfl_xor(t0, 1); t0 += __shfl_xor(t0, 2);
        t1 += __shfl_xor(t1, 1); t1 += __shfl_xor(t1, 2);
        t2 += __shfl_xor(t2, 1); t2 += __shfl_xor(t2, 2);
        ls += __shfl_xor(ls, 1); ls += __shfl_xor(ls, 2);
        if (q == 0) *(float4*)(tt + r * 4) = make_float4(t0, t1, t2, ls);
        __syncthreads();
        const float wv0 = a_vw[t * 3], wv1 = a_vw[t * 3 + 1], wv2 = a_vw[t * 3 + 2];
        const float bv = a_vb[t];
        unsigned short* Ob = ctxT + ((long)z * 1026 + 1 + l0) * 256;
        for (int rr = 0; rr < 64; ++rr) {
            const float4 th = *(const float4*)(tt + rr * 4);
            const float inv = 1.f / th.w;
            Ob[(long)rr * 256 + t] = f2bf((wv0 * th.x + wv1 * th.y + wv2 * th.z) * inv + bv);
        }
    } else {
        // ---------------- branch b ----------------
        const int b2 = bid - 256;
        const int z = b2 & 15;
        const int l0 = (b2 >> 4) << 4;
        const int li = t >> 4, mg = t & 15;
        const int l = l0 + li;
        const float x0 = (l >= 1) ? cli[(long)z * 1024 + l - 1] : 0.f;
        const float x1 = cli[(long)z * 1024 + l];
        const float x2 = (l < 1023) ? cli[(long)z * 1024 + l + 1] : 0.f;
        const float4* Yz = (const float4*)(M4Y + (long)z * 4096);
        unsigned short* Pr = P + ((long)z * 1024 + l) * 1024;
        float lsum = 0.f;
#pragma unroll
        for (int jc = 0; jc < 4; ++jc)
#pragma unroll
            for (int i8 = 0; i8 < 2; ++i8) {
                const int mb = jc * 256 + mg * 16 + i8 * 8;
                bf16x8 out;
#pragma unroll
                for (int e = 0; e < 8; ++e) {
                    const float4 y = Yz[mb + e];
                    const float p = __expf(x0 * y.x + x1 * y.y + x2 * y.z + y.w);
                    lsum += p;
                    out[e] = (short)f2bf(p);
                }
                *(bf16x8*)(Pr + mb) = out;
            }
        lsum += __shfl_xor(lsum, 1); lsum += __shfl_xor(lsum, 2);
        lsum += __shfl_xor(lsum, 4); lsum += __shfl_xor(lsum, 8);
        if (mg == 0) invl[(long)z * 1024 + l] = 1.f / lsum;
    }
}

// ---------------------------------------------------------------------------
// Fused prep (grid 3432): imgT transpose (1024), W pack for vb/oa/ob (2304),
// pad+sums zeroing (100), EF weight-contraction (3), consts (1).
// ---------------------------------------------------------------------------
__global__ __launch_bounds__(256)
void prep(const float* __restrict__ image,
          const float* __restrict__ a_qw, const float* __restrict__ a_qb,
          const float* __restrict__ a_kw, const float* __restrict__ a_kb,
          const float* __restrict__ b_qw, const float* __restrict__ b_qb,
          const float* __restrict__ b_kw, const float* __restrict__ b_kb,
          const float* __restrict__ b_vw,
          const float* __restrict__ a_ow, const float* __restrict__ b_ow,
          unsigned short* __restrict__ imgT, unsigned short* __restrict__ ctxT,
          unsigned short* __restrict__ W,
          float* __restrict__ EF, float* __restrict__ cst,
          float* __restrict__ sums)
{
    __shared__ char smem[64 * 65 * 4];
    const int b = blockIdx.x;
    const int t = threadIdx.x;
    if (b < 1024) {
        float* tile = (float*)smem;                      // [64][65]
        const int bt = b >> 6, rem = b & 63;
        const int l0 = (rem & 15) * 64, c0 = (rem >> 4) * 64;
        const float* xb = image + ((long)bt * 256 + c0) * 1024 + l0;
        for (int idx = t; idx < 4096; idx += 256) {
            const int cc = idx >> 6, ll = idx & 63;
            tile[cc * 65 + ll] = xb[(long)cc * 1024 + ll];
        }
        __syncthreads();
        unsigned short* op = imgT + ((long)bt * 1026 + l0 + 1) * 256 + c0;
        for (int idx = t; idx < 4096; idx += 256) {
            const int ll = idx >> 6, cc = idx & 63;
            op[(long)ll * 256 + cc] = f2bf(tile[cc * 65 + ll]);
        }
    } else if (b < 3328) {
        const int i = (b - 1024) * 256 + t;              // 0..589823
        const int row = i / 768;
        const int kk = i - row * 768;
        const int j = kk >> 8, ci = kk & 255;
        const float* src = (row < 256) ? b_vw : (row < 512) ? a_ow : b_ow;
        const int r = row & 255;
        W[i] = f2bf(src[r * 768 + ci * 3 + j]);
    } else if (b < 3428) {
        const int i = (b - 3328) * 256 + t;              // 0..25599
        if (i < 8192) {
            const int bi = i >> 9, rr = (i >> 8) & 1, c = i & 255;
            imgT[((long)bi * 1026 + (rr ? 1025 : 0)) * 256 + c] = 0;
        } else if (i < 8192 + 16384) {
            const int p = i - 8192;                      // ctxT pad rows
            const int bz = p >> 9, rr = (p >> 8) & 1, c = p & 255;
            ctxT[((long)bz * 1026 + (rr ? 1025 : 0)) * 256 + c] = 0;
        } else {
            sums[i - 8192 - 16384] = 0.f;                // BN accumulators
        }
    } else if (b < 3431) {
        // EF[k][0..3] = sum_c a_qw[c][ci][j] * (a_kw[c][j'], a_kb[c]) / 16
        // EF[k][4..7] = sum_c b_kw[c][ci][j] * (b_qw[c][j'], b_qb[c]) / 16
        const int k = (b - 3428) * 256 + t;              // 0..767
        const int ci = k & 255, j = k >> 8;
        float e0 = 0.f, e1 = 0.f, e2 = 0.f, e3 = 0.f;
        float f0 = 0.f, f1 = 0.f, f2 = 0.f, f3 = 0.f;
        for (int c = 0; c < 256; ++c) {
            const float qa = a_qw[c * 768 + ci * 3 + j];
            e0 += qa * a_kw[c * 3];     e1 += qa * a_kw[c * 3 + 1];
            e2 += qa * a_kw[c * 3 + 2]; e3 += qa * a_kb[c];
            const float kb = b_kw[c * 768 + ci * 3 + j];
            f0 += kb * b_qw[c * 3];     f1 += kb * b_qw[c * 3 + 1];
            f2 += kb * b_qw[c * 3 + 2]; f3 += kb * b_qb[c];
        }
        float* o = EF + (long)k * 8;
        o[0] = e0 * 0.0625f; o[1] = e1 * 0.0625f; o[2] = e2 * 0.0625f; o[3] = e3 * 0.0625f;
        o[4] = f0 * 0.0625f; o[5] = f1 * 0.0625f; o[6] = f2 * 0.0625f; o[7] = f3 * 0.0625f;
    } else {
        // consts: e0[j'] = sum_c a_qb[c]*a_kw[c][j'] (e0[3] with a_kb);
        //         f0[j'] = sum_c b_kb[c]*b_qw[c][j'] (f0[3] with b_qb)
        if (t < 8) {
            float s = 0.f;
            if (t < 4) {
                for (int c = 0; c < 256; ++c)
                    s += a_qb[c] * ((t < 3) ? a_kw[c * 3 + t] : a_kb[c]);
            } else {
                for (int c = 0; c < 256; ++c)
                    s += b_kb[c] * ((t < 7) ? b_qw[c * 3 + (t - 4)] : b_qb[c]);
            }
            cst[t] = s * 0.0625f;
        }
    }
}

// ---------------------------------------------------------------------------
// BN finalize: sums[ch], sums[512+ch] -> ss scale/shift.  2 blocks.
// ---------------------------------------------------------------------------
__global__ __launch_bounds__(256)
void bn_finalize(const float* __restrict__ sums,
                 const float* __restrict__ ag, const float* __restrict__ abeta,
                 const float* __restrict__ bg, const float* __restrict__ bbeta,
                 float* __restrict__ ss)
{
    const int ch = blockIdx.x * 256 + threadIdx.x;
    const int branch = ch >> 8, c = ch & 255;
    const float mean = sums[ch] * (1.f / 16384.f);
    const float var = sums[512 + ch] * (1.f / 16384.f) - mean * mean;  // biased
    const float inv = rsqrtf(var + 1e-5f);
    const float g = branch ? bg[c] : ag[c];
    const float be = branch ? bbeta[c] : abeta[c];
    const float sc = g * inv;
    ss[ch] = sc;
    ss[512 + ch] = be - mean * sc;
}

// out[b][ch][l] = y*scale + shift + image[b][ch&255][l]  (Y is bf16)
__global__ __launch_bounds__(256)
void bn_apply(const unsigned short* __restrict__ Y, const float* __restrict__ img,
              const float* __restrict__ ss, float* __restrict__ out)
{
    const long i4 = (long)blockIdx.x * 256 + threadIdx.x;
    const long e = i4 * 4;
    const int l = (int)(e & 1023);
    const int ch = (int)((e >> 10) & 511);
    const int b = (int)(e >> 19);
    const int branch = ch >> 8, c = ch & 255;
    const float sc = ss[ch], sh = ss[512 + ch];
    const long yoff = (((long)(branch * 16 + b)) * 256 + c) * 1024 + l;
    const long ioff = ((long)b * 256 + c) * 1024 + l;
    const ushort4 yv = *(const ushort4*)(Y + yoff);
    const float4 iv = *(const float4*)(img + ioff);
    float4 o;
    o.x = bf2f(yv.x) * sc + sh + iv.x;
    o.y = bf2f(yv.y) * sc + sh + iv.y;
    o.z = bf2f(yv.z) * sc + sh + iv.z;
    o.w = bf2f(yv.w) * sc + sh + iv.w;
    *(float4*)(out + e) = o;
}

// ---------------------------------------------------------------------------
extern "C" void kernel_launch(void* const* d_in, const int* in_sizes, int n_in,
                              void* d_out, int out_size, void* d_ws, size_t ws_size,
                              hipStream_t stream)
{
    const float* image    = (const float*)d_in[0];
    const float* clinical = (const float*)d_in[1];
    const float* a_qw = (const float*)d_in[2];  const float* a_qb = (const float*)d_in[3];
    const float* a_kw = (const float*)d_in[4];  const float* a_kb = (const float*)d_in[5];
    const float* a_vw = (const float*)d_in[6];  const float* a_vb = (const float*)d_in[7];
    const float* a_ow = (const float*)d_in[8];  const float* a_ob = (const float*)d_in[9];
    const float* a_g  = (const float*)d_in[10]; const float* a_be = (const float*)d_in[11];
    const float* b_qw = (const float*)d_in[12]; const float* b_qb = (const float*)d_in[13];
    const float* b_kw = (const float*)d_in[14]; const float* b_kb = (const float*)d_in[15];
    const float* b_vw = (const float*)d_in[16]; const float* b_vb = (const float*)d_in[17];
    const float* b_ow = (const float*)d_in[18]; const float* b_ob = (const float*)d_in[19];
    const float* b_g  = (const float*)d_in[20]; const float* b_be = (const float*)d_in[21];
    float* out = (float*)d_out;

    char* ws = (char*)d_ws;
    const long MB = 1048576L;
    unsigned short* imgT = (unsigned short*)(ws);              // [16][1026][256] bf16
    unsigned short* ctxT = (unsigned short*)(ws + 9 * MB);     // [32][1026][256] bf16
    unsigned short* vb   = (unsigned short*)(ws + 54 * MB);    // [16][256][1024]
    unsigned short* P    = (unsigned short*)(ws + 80 * MB);    // [16][1024][1024] bf16
    float*          M4A  = (float*)(ws + 114 * MB);            // [16][1024][4]
    float*          M4Y  = (float*)(ws + 115 * MB);            // [16][1024][4]
    float*          invl = (float*)(ws + 116 * MB);            // [16][1024]
    unsigned short* Y    = (unsigned short*)(ws + 142 * MB);   // [32][256][1024] bf16
    unsigned short* W    = (unsigned short*)(ws + 174 * MB);   // [768][768] bf16 tap-major
    float*          EF   = (float*)(ws + 176 * MB);            // [768][8]
    float*          cst  = EF + 6144;     // 8 f32
    float*          ss   = EF + 6208;     // 1024 f32
    float*          sums = EF + 7232;     // 1024 f32 (BN accumulators)
    unsigned short* Wvb = W;
    unsigned short* Woa = W + 256L * 768;
    unsigned short* Wob = W + 512L * 768;

    const dim3 blk(256);
    const long sIT = 1026L * 256, sV = 256L * 1024;
    const long sP = 1024L * 1024;

    prep<<<3432, blk, 0, stream>>>(image, a_qw, a_qb, a_kw, a_kb,
                                   b_qw, b_qb, b_kw, b_kb, b_vw, a_ow, b_ow,
                                   imgT, ctxT, W, EF, cst, sums);
    // Dispatch 2: rank-4 A,d / Y,c from imgT windows (replaces QK GEMM + mats)
    matsAY<<<256, blk, 0, stream>>>(imgT, EF, cst, M4A, M4Y);
    // Dispatch 3: branch-a streaming attention -> ctxT[0..16); branch-b P gen
    attn_mid<<<1280, blk, 0, stream>>>(clinical, M4A, M4Y, a_vw, a_vb,
                                       P, invl, ctxT);
    // Dispatch 4: vb[co][l] GEMM (K=768)
    {
        GOp opV = {Wvb, imgT, vb, 0, sIT, sV, 768, 256, 1024, 8, 2, 16, 768,
                   b_vb, nullptr, nullptr, nullptr, 0};
        gemm_nt<<<256, blk, 0, stream>>>(opV, opV, 256, 1.f);
    }
    // Dispatch 5: o-conv-a (-> Y bf16 + BN stats)  ||  PV_b (-> ctxT[16..32))
    {
        GOp opA = {Woa, ctxT, Y, 0, sIT, sV, 768, 256, 1024, 8, 2, 16, 768,
                   a_ob, nullptr, nullptr, sums, 0};
        GOp opPV = {P, vb, ctxT + 16 * sIT + 256, sP, sV, sIT, 1024, 1024, 256,
                    2, 8, 16, 1024, nullptr, nullptr, invl, nullptr, 0};
        gemm_nt<<<512, blk, 0, stream>>>(opA, opPV, 256, 1.f);
    }
    // Dispatch 6: o-conv-b -> Y bf16 + BN stats
    {
        GOp opB = {Wob, ctxT + 16 * sIT, Y + 16 * sV, 0, sIT, sV, 768, 256, 1024,
                   8, 2, 16, 768, b_ob, nullptr, nullptr, sums, 256};
        gemm_nt<<<256, blk, 0, stream>>>(opB, opB, 256, 1.f);
    }
    // BN finalize + apply
    bn_finalize<<<2, blk, 0, stream>>>(sums, a_g, a_be, b_g, b_be, ss);
    bn_apply<<<8192, blk, 0, stream>>>(Y, image, ss, out);
}

// Round 8
// 267.351 us; speedup vs baseline: 1.1720x; 1.1720x over previous
//
#include <hip/hip_runtime.h>

// CrossSymmetricModal: two cross-attention branches. B=16, C=256, L=1024.
// R15: rank-4 algebra (clinical is [B,1,L]) -- branch-a attention is a
// streaming VALU kernel; branch-b QK^T is rank-4; P_b materialized bf16,
// PV + o-convs run in the proven gemm_nt (glds16 double-buffered).
// R16: attn_mid re-gridded for occupancy (1280 blocks).
// R18: revert R17's matsAY experiment (48us: 1 block/CU latency-bound, the
// grid-64 mats had the same disease).  Keep R16's QK-GEMM pipeline; fix
// mats occupancy: grid 64 -> 1024 (16 rows/block, 16 thr/row, 32-ch slices,
// shfl_xor octet reduce).  Rule: streaming kernels need >=2048 blocks or
// >=4 waves/SIMD with independent unrolled loads.
// Output [16][512][1024] fp32.

typedef short bf16x8 __attribute__((ext_vector_type(8)));
typedef float f32x4 __attribute__((ext_vector_type(4)));

__device__ __forceinline__ unsigned short f2bf(float f) {
    union { float f; unsigned u; } v; v.f = f;
    unsigned r = v.u + 0x7fffu + ((v.u >> 16) & 1u);   // RNE
    return (unsigned short)(r >> 16);
}
__device__ __forceinline__ float bf2f(unsigned short h) {
    union { unsigned u; float f; } v; v.u = ((unsigned)h) << 16;
    return v.f;
}

// async global->LDS, 16B per lane; HW writes lane i at lds_base + i*16 (m97/m104)
__device__ __forceinline__ void glds16(const void* g, void* l) {
    __builtin_amdgcn_global_load_lds(
        (const __attribute__((address_space(1))) unsigned int*)g,
        (__attribute__((address_space(3))) unsigned int*)l, 16, 0, 0);
}

// ---------------------------------------------------------------------------
// NT GEMM: 2-op batched, compact 1-D grid, double-buffered glds staging,
// LDS-transpose epilogue with coalesced 16B stores.  Per-op K; optional
// epilogue row-scale (PV normalization) and BN partial-stats atomics.
// ---------------------------------------------------------------------------
#define TM 128
#define TN 128
#define BK 32

struct GOp {
    const unsigned short* A; const unsigned short* B; void* C;
    long sA, sB, sC;
    int lda, ldb, ldc, nxt, nyt, nz, K;
    const float* bias_row; const float* bias_col;
    const float* row_scale;           // scale C row (i0+row) by rs[bz*M + row]
    float* stats; int stat_base;      // stats!=null: atomicAdd sum/sumsq per row
};

__global__ __launch_bounds__(256)
void gemm_nt(GOp op0, GOp op1, int n0, float alpha)
{
    __shared__ __attribute__((aligned(16))) char sh[34816];
    unsigned short* shs = (unsigned short*)sh;
    int id = blockIdx.x;
    const bool brn = (id >= n0);
    const GOp op = brn ? op1 : op0;
    if (brn) id -= n0;
    const int bz = id % op.nz;          // XCD swizzle
    const int rem = id / op.nz;
    const int by = rem / op.nxt;
    const int bx = rem - by * op.nxt;

    const unsigned short* Ab = op.A + op.sA * bz;
    const unsigned short* Bb = op.B + op.sB * bz;
    const int lda = op.lda, ldb = op.ldb;
    const int i0 = by * TM;
    const int j0 = bx * TN;
    const int t = threadIdx.x;
    const int lane = t & 63;
    const int wave = t >> 6;
    const int wm = wave & 1, wn = wave >> 1;

    const int srow = wave * 16 + (lane >> 2);
    const int sc8 = (lane & 3) * 8;
    const unsigned short* gA0 = Ab + (long)(i0 + srow) * lda + sc8;
    const unsigned short* gA1 = gA0 + (long)64 * lda;
    const unsigned short* gB0 = Bb + (long)(j0 + srow) * ldb + sc8;
    const unsigned short* gB1 = gB0 + (long)64 * ldb;
    const int d0 = wave * 512;
    const int d1 = 2048 + wave * 512;

    f32x4 acc[4][4];
#pragma unroll
    for (int a_ = 0; a_ < 4; ++a_)
#pragma unroll
        for (int b_ = 0; b_ < 4; ++b_)
            acc[a_][b_] = (f32x4){0.f, 0.f, 0.f, 0.f};

    const int frow = lane & 15;
    const int fk = (lane >> 4) * 8;

    glds16(gA0, shs + d0);
    glds16(gA1, shs + d1);
    glds16(gB0, shs + 8192 + d0);
    glds16(gB1, shs + 8192 + d1);

    int cur = 0;
    for (int k0 = 0; k0 < op.K; k0 += BK) {
        __syncthreads();
        const int kn = k0 + BK;
        if (kn < op.K) {
            const int nb = cur ^ 1;
            glds16(gA0 + kn, shs + nb * 4096 + d0);
            glds16(gA1 + kn, shs + nb * 4096 + d1);
            glds16(gB0 + kn, shs + 8192 + nb * 4096 + d0);
            glds16(gB1 + kn, shs + 8192 + nb * 4096 + d1);
        }
        const unsigned short* la = shs + cur * 4096;
        const unsigned short* lb = shs + 8192 + cur * 4096;
        bf16x8 af[4], bfr[4];
#pragma unroll
        for (int mt = 0; mt < 4; ++mt)
            af[mt] = *(const bf16x8*)(&la[(wm * 64 + mt * 16 + frow) * BK + fk]);
#pragma unroll
        for (int nt = 0; nt < 4; ++nt)
            bfr[nt] = *(const bf16x8*)(&lb[(wn * 64 + nt * 16 + frow) * BK + fk]);
#pragma unroll
        for (int mt = 0; mt < 4; ++mt)
#pragma unroll
            for (int nt = 0; nt < 4; ++nt)
                acc[mt][nt] = __builtin_amdgcn_mfma_f32_16x16x32_bf16(af[mt], bfr[nt], acc[mt][nt], 0, 0, 0);
        cur ^= 1;
    }

    const int lr = (lane >> 4) * 4;   // C/D: row=(lane>>4)*4+reg, col=lane&15 (m89/m91)
    const int lc = lane & 15;
    __syncthreads();

    unsigned short* tile = shs;       // [128][136]
#pragma unroll
    for (int mt = 0; mt < 4; ++mt) {
#pragma unroll
        for (int nt = 0; nt < 4; ++nt) {
            const int col = wn * 64 + nt * 16 + lc;
            const float bc = op.bias_col ? op.bias_col[j0 + col] : 0.f;
#pragma unroll
            for (int r = 0; r < 4; ++r) {
                const int row = wm * 64 + mt * 16 + lr + r;
                const float brv = op.bias_row ? op.bias_row[i0 + row] : 0.f;
                const float rsv = op.row_scale
                    ? op.row_scale[(long)bz * (op.nyt * TM) + i0 + row] : 1.f;
                tile[row * 136 + col] = f2bf((acc[mt][nt][r] * alpha + brv + bc) * rsv);
            }
        }
    }
    __syncthreads();
    unsigned short* Cb = (unsigned short*)op.C + op.sC * bz;
#pragma unroll
    for (int p = 0; p < 8; ++p) {
        const int cid = p * 256 + t;
        const int row = cid >> 4;
        const int c8 = (cid & 15) * 8;
        const uint4 v = *(const uint4*)(tile + row * 136 + c8);
        *(uint4*)(Cb + (long)(i0 + row) * op.ldc + j0 + c8) = v;
    }
    if (op.stats) {
        // per-channel (row) partial sums of the bf16 tile; 2 threads/row
        const int row = t >> 1, half = t & 1;
        float s = 0.f, s2 = 0.f;
#pragma unroll
        for (int c = 0; c < 64; c += 8) {
            const bf16x8 v = *(const bf16x8*)(tile + row * 136 + half * 64 + c);
#pragma unroll
            for (int e = 0; e < 8; ++e) {
                const float f = bf2f((unsigned short)v[e]);
                s += f; s2 += f * f;
            }
        }
        s += __shfl_xor(s, 1);
        s2 += __shfl_xor(s2, 1);
        if (half == 0) {
            const int ch = op.stat_base + i0 + row;
            atomicAdd(&op.stats[ch], s);
            atomicAdd(&op.stats[512 + ch], s2);
        }
    }
}

// ---------------------------------------------------------------------------
// mats (R18): per (z,l) row of QK buffer ([l][512]: cols 0-255 = Q_a,
// 256-511 = K_b):
//   A[l][j] = sum_c Q_a[c][l] a_kw[c][j],  d[l] = sum_c Q_a[c][l] a_kb[c]
//   Y[m][j] = sum_c K_b[c][m] b_qw[c][j],  cb[m] = sum_c K_b[c][m] b_qb[c]
// Grid 1024 = 16 z x 64 chunks of 16 rows.  16 thr/row: q 0-7 contract Q_a
// channels q*32..+32, q 8-15 contract K_b channels; shfl_xor(1,2,4) octet
// reduce; q==0 writes M4A, q==8 writes M4Y.  4 blocks/CU, no LDS.
// ---------------------------------------------------------------------------
__global__ __launch_bounds__(256)
void mats(const unsigned short* __restrict__ QK,
          const float* __restrict__ a_kw, const float* __restrict__ a_kb,
          const float* __restrict__ b_qw, const float* __restrict__ b_qb,
          float* __restrict__ M4A, float* __restrict__ M4Y)
{
    const int bid = blockIdx.x;           // 1024 = 16 z (fastest) x 64 chunks
    const int z = bid & 15, chk = bid >> 4;
    const int t = threadIdx.x;
    const int r = t >> 4, q = t & 15;
    const int l = chk * 16 + r;
    const bool isY = q >= 8;
    const int c0 = (q & 7) * 32;
    const unsigned short* row = QK + ((long)z * 1024 + l) * 512
                                + (isY ? 256 : 0) + c0;
    const float* w3 = isY ? b_qw : a_kw;
    const float* wb = isY ? b_qb : a_kb;
    float s0 = 0.f, s1 = 0.f, s2 = 0.f, s3 = 0.f;
#pragma unroll
    for (int i8 = 0; i8 < 4; ++i8) {
        const bf16x8 x8 = *(const bf16x8*)(row + i8 * 8);
#pragma unroll
        for (int e = 0; e < 8; ++e) {
            const int c = c0 + i8 * 8 + e;
            const float xv = bf2f((unsigned short)x8[e]);
            s0 += xv * w3[c * 3];
            s1 += xv * w3[c * 3 + 1];
            s2 += xv * w3[c * 3 + 2];
            s3 += xv * wb[c];
        }
    }
    s0 += __shfl_xor(s0, 1); s0 += __shfl_xor(s0, 2); s0 += __shfl_xor(s0, 4);
    s1 += __shfl_xor(s1, 1); s1 += __shfl_xor(s1, 2); s1 += __shfl_xor(s1, 4);
    s2 += __shfl_xor(s2, 1); s2 += __shfl_xor(s2, 2); s2 += __shfl_xor(s2, 4);
    s3 += __shfl_xor(s3, 1); s3 += __shfl_xor(s3, 2); s3 += __shfl_xor(s3, 4);
    if ((q & 7) == 0) {
        const long o = ((long)z * 1024 + l) * 4;
        const float4 v = make_float4(s0, s1, s2, s3);
        if (isY) *(float4*)(M4Y + o) = v;
        else     *(float4*)(M4A + o) = v;
    }
}

// ---------------------------------------------------------------------------
// attn_mid, grid 1280 (R16):
//  bid<256: branch a. Block = (z = bid&15, 64-row chunk).  4 threads/row
//    stream 256 m each (xs in LDS), shfl_xor(1,2) reduce, t_hat to LDS;
//    epilogue: thread=channel writes ctx_a[c][l] for the 64 rows.
//  bid>=256: branch b. Block = (z, 16-row chunk), 16 threads/row.  NO LDS:
//    y as coalesced float4 from global (L1-resident), P direct bf16x8 to
//    global, rowsum via shfl_xor over mg=t&15, invl by mg==0.
// ---------------------------------------------------------------------------
__global__ __launch_bounds__(256)
void attn_mid(const float* __restrict__ cli,
              const float* __restrict__ M4A, const float* __restrict__ M4Y,
              const float* __restrict__ a_vw, const float* __restrict__ a_vb,
              unsigned short* __restrict__ P, float* __restrict__ invl,
              unsigned short* __restrict__ ctxT)
{
    __shared__ __attribute__((aligned(16))) float smem[1032 + 256];  // xs | tt
    const int bid = blockIdx.x;
    const int t = threadIdx.x;
    if (bid < 256) {
        // ---------------- branch a ----------------
        const int z = bid & 15;
        const int l0 = (bid >> 4) << 6;
        float* xs = smem;                               // [1026]
        float* tt = smem + 1032;                        // [64][4]
        for (int i = t; i < 1026; i += 256) {
            const int l = i - 1;
            xs[i] = (l >= 0 && l < 1024) ? cli[(long)z * 1024 + l] : 0.f;
        }
        __syncthreads();
        const int r = t >> 2, q = t & 3;
        const float4 A = *(const float4*)(M4A + ((long)z * 1024 + l0 + r) * 4);
        float t0 = 0.f, t1 = 0.f, t2 = 0.f, ls = 0.f;
        const int m0 = q * 256;
#pragma unroll 4
        for (int m = m0; m < m0 + 256; ++m) {
            const float x0 = xs[m], x1 = xs[m + 1], x2 = xs[m + 2];
            const float e = __expf((A.x * x0 + A.y * x1 + A.z * x2 + A.w) * 0.0625f);
            t0 += e * x0; t1 += e * x1; t2 += e * x2; ls += e;
        }
        t0 += __shfl_xor(t0, 1); t0 += __shfl_xor(t0, 2);
        t1 += __shfl_xor(t1, 1); t1 += __shfl_xor(t1, 2);
        t2 += __shfl_xor(t2, 1); t2 += __shfl_xor(t2, 2);
        ls += __shfl_xor(ls, 1); ls += __shfl_xor(ls, 2);
        if (q == 0) *(float4*)(tt + r * 4) = make_float4(t0, t1, t2, ls);
        __syncthreads();
        const float wv0 = a_vw[t * 3], wv1 = a_vw[t * 3 + 1], wv2 = a_vw[t * 3 + 2];
        const float bv = a_vb[t];
        unsigned short* Ob = ctxT + ((long)z * 1026 + 1 + l0) * 256;
        for (int rr = 0; rr < 64; ++rr) {
            const float4 th = *(const float4*)(tt + rr * 4);
            const float inv = 1.f / th.w;
            Ob[(long)rr * 256 + t] = f2bf((wv0 * th.x + wv1 * th.y + wv2 * th.z) * inv + bv);
        }
    } else {
        // ---------------- branch b ----------------
        const int b2 = bid - 256;
        const int z = b2 & 15;
        const int l0 = (b2 >> 4) << 4;
        const int li = t >> 4, mg = t & 15;
        const int l = l0 + li;
        const float x0 = (l >= 1) ? cli[(long)z * 1024 + l - 1] : 0.f;
        const float x1 = cli[(long)z * 1024 + l];
        const float x2 = (l < 1023) ? cli[(long)z * 1024 + l + 1] : 0.f;
        const float4* Yz = (const float4*)(M4Y + (long)z * 4096);
        unsigned short* Pr = P + ((long)z * 1024 + l) * 1024;
        float lsum = 0.f;
#pragma unroll
        for (int jc = 0; jc < 4; ++jc)
#pragma unroll
            for (int i8 = 0; i8 < 2; ++i8) {
                const int mb = jc * 256 + mg * 16 + i8 * 8;
                bf16x8 out;
#pragma unroll
                for (int e = 0; e < 8; ++e) {
                    const float4 y = Yz[mb + e];
                    const float p = __expf((x0 * y.x + x1 * y.y + x2 * y.z + y.w) * 0.0625f);
                    lsum += p;
                    out[e] = (short)f2bf(p);
                }
                *(bf16x8*)(Pr + mb) = out;
            }
        lsum += __shfl_xor(lsum, 1); lsum += __shfl_xor(lsum, 2);
        lsum += __shfl_xor(lsum, 4); lsum += __shfl_xor(lsum, 8);
        if (mg == 0) invl[(long)z * 1024 + l] = 1.f / lsum;
    }
}

// ---------------------------------------------------------------------------
// Fused prep (grid 4966): imgT transpose, W pack, qkb, pad zeroing, BN sums.
// ---------------------------------------------------------------------------
__global__ __launch_bounds__(256)
void prep(const float* __restrict__ image,
          const float* __restrict__ a_qw, const float* __restrict__ a_qb,
          const float* __restrict__ b_kw, const float* __restrict__ b_kb,
          const float* __restrict__ b_vw,
          const float* __restrict__ a_ow, const float* __restrict__ b_ow,
          unsigned short* __restrict__ imgT, unsigned short* __restrict__ ctxT,
          unsigned short* __restrict__ W, float* __restrict__ qkb,
          float* __restrict__ sums)
{
    __shared__ char smem[64 * 65 * 4];
    const int b = blockIdx.x;
    const int t = threadIdx.x;
    if (b < 1024) {
        float* tile = (float*)smem;                      // [64][65]
        const int bt = b >> 6, rem = b & 63;
        const int l0 = (rem & 15) * 64, c0 = (rem >> 4) * 64;
        const float* xb = image + ((long)bt * 256 + c0) * 1024 + l0;
        for (int idx = t; idx < 4096; idx += 256) {
            const int cc = idx >> 6, ll = idx & 63;
            tile[cc * 65 + ll] = xb[(long)cc * 1024 + ll];
        }
        __syncthreads();
        unsigned short* op = imgT + ((long)bt * 1026 + l0 + 1) * 256 + c0;
        for (int idx = t; idx < 4096; idx += 256) {
            const int ll = idx >> 6, cc = idx & 63;
            op[(long)ll * 256 + cc] = f2bf(tile[cc * 65 + ll]);
        }
    } else if (b < 4864) {
        const int i = (b - 1024) * 256 + t;              // 0..983039
        const int row = i / 768;
        const int kk = i - row * 768;
        const int j = kk >> 8, ci = kk & 255;
        const float* src = (row < 256) ? a_qw : (row < 512) ? b_kw
                         : (row < 768) ? b_vw : (row < 1024) ? a_ow : b_ow;
        const int r = row & 255;
        W[i] = f2bf(src[r * 768 + ci * 3 + j]);
    } else {
        const int i = (b - 4864) * 256 + t;              // 0..26111
        if (i < 512) {
            qkb[i] = (i < 256) ? a_qb[i] : b_kb[i - 256];
        } else if (i < 512 + 8192) {
            const int p = i - 512;                       // imgT pad rows
            const int bi = p >> 9, rr = (p >> 8) & 1, c = p & 255;
            imgT[((long)bi * 1026 + (rr ? 1025 : 0)) * 256 + c] = 0;
        } else if (i < 512 + 8192 + 16384) {
            const int p = i - 512 - 8192;                // ctxT pad rows
            const int bz = p >> 9, rr = (p >> 8) & 1, c = p & 255;
            ctxT[((long)bz * 1026 + (rr ? 1025 : 0)) * 256 + c] = 0;
        } else if (i < 512 + 8192 + 16384 + 1024) {
            sums[i - 512 - 8192 - 16384] = 0.f;          // BN accumulators
        }
    }
}

// ---------------------------------------------------------------------------
// BN finalize: sums[ch], sums[512+ch] -> ss scale/shift.  2 blocks.
// ---------------------------------------------------------------------------
__global__ __launch_bounds__(256)
void bn_finalize(const float* __restrict__ sums,
                 const float* __restrict__ ag, const float* __restrict__ abeta,
                 const float* __restrict__ bg, const float* __restrict__ bbeta,
                 float* __restrict__ ss)
{
    const int ch = blockIdx.x * 256 + threadIdx.x;
    const int branch = ch >> 8, c = ch & 255;
    const float mean = sums[ch] * (1.f / 16384.f);
    const float var = sums[512 + ch] * (1.f / 16384.f) - mean * mean;  // biased
    const float inv = rsqrtf(var + 1e-5f);
    const float g = branch ? bg[c] : ag[c];
    const float be = branch ? bbeta[c] : abeta[c];
    const float sc = g * inv;
    ss[ch] = sc;
    ss[512 + ch] = be - mean * sc;
}

// out[b][ch][l] = y*scale + shift + image[b][ch&255][l]  (Y is bf16)
__global__ __launch_bounds__(256)
void bn_apply(const unsigned short* __restrict__ Y, const float* __restrict__ img,
              const float* __restrict__ ss, float* __restrict__ out)
{
    const long i4 = (long)blockIdx.x * 256 + threadIdx.x;
    const long e = i4 * 4;
    const int l = (int)(e & 1023);
    const int ch = (int)((e >> 10) & 511);
    const int b = (int)(e >> 19);
    const int branch = ch >> 8, c = ch & 255;
    const float sc = ss[ch], sh = ss[512 + ch];
    const long yoff = (((long)(branch * 16 + b)) * 256 + c) * 1024 + l;
    const long ioff = ((long)b * 256 + c) * 1024 + l;
    const ushort4 yv = *(const ushort4*)(Y + yoff);
    const float4 iv = *(const float4*)(img + ioff);
    float4 o;
    o.x = bf2f(yv.x) * sc + sh + iv.x;
    o.y = bf2f(yv.y) * sc + sh + iv.y;
    o.z = bf2f(yv.z) * sc + sh + iv.z;
    o.w = bf2f(yv.w) * sc + sh + iv.w;
    *(float4*)(out + e) = o;
}

// ---------------------------------------------------------------------------
extern "C" void kernel_launch(void* const* d_in, const int* in_sizes, int n_in,
                              void* d_out, int out_size, void* d_ws, size_t ws_size,
                              hipStream_t stream)
{
    const float* image    = (const float*)d_in[0];
    const float* clinical = (const float*)d_in[1];
    const float* a_qw = (const float*)d_in[2];  const float* a_qb = (const float*)d_in[3];
    const float* a_kw = (const float*)d_in[4];  const float* a_kb = (const float*)d_in[5];
    const float* a_vw = (const float*)d_in[6];  const float* a_vb = (const float*)d_in[7];
    const float* a_ow = (const float*)d_in[8];  const float* a_ob = (const float*)d_in[9];
    const float* a_g  = (const float*)d_in[10]; const float* a_be = (const float*)d_in[11];
    const float* b_qw = (const float*)d_in[12]; const float* b_qb = (const float*)d_in[13];
    const float* b_kw = (const float*)d_in[14]; const float* b_kb = (const float*)d_in[15];
    const float* b_vw = (const float*)d_in[16]; const float* b_vb = (const float*)d_in[17];
    const float* b_ow = (const float*)d_in[18]; const float* b_ob = (const float*)d_in[19];
    const float* b_g  = (const float*)d_in[20]; const float* b_be = (const float*)d_in[21];
    float* out = (float*)d_out;

    char* ws = (char*)d_ws;
    const long MB = 1048576L;
    unsigned short* imgT = (unsigned short*)(ws);              // [16][1026][256] bf16
    unsigned short* ctxT = (unsigned short*)(ws + 9 * MB);     // [32][1026][256] bf16
    unsigned short* vb   = (unsigned short*)(ws + 54 * MB);    // [16][256][1024]
    unsigned short* QK   = (unsigned short*)(ws + 62 * MB);    // [16][1024][512]
    unsigned short* P    = (unsigned short*)(ws + 80 * MB);    // [16][1024][1024] bf16
    float*          M4A  = (float*)(ws + 114 * MB);            // [16][1024][4]
    float*          M4Y  = (float*)(ws + 115 * MB);            // [16][1024][4]
    float*          invl = (float*)(ws + 116 * MB);            // [16][1024]
    unsigned short* Y    = (unsigned short*)(ws + 142 * MB);   // [32][256][1024] bf16
    unsigned short* W    = (unsigned short*)(ws + 174 * MB);   // [1280][768] bf16 tap-major
    float*          qkb  = (float*)(ws + 176 * MB);
    float*          ss   = qkb + 512;     // 1024 f32
    float*          sums = qkb + 1536;    // 1024 f32 (BN accumulators)
    unsigned short* Wqk = W;
    unsigned short* Wvb = W + 512L * 768;
    unsigned short* Woa = W + 768L * 768;
    unsigned short* Wob = W + 1024L * 768;

    const dim3 blk(256);
    const long sIT = 1026L * 256, sQK = 1024L * 512, sV = 256L * 1024;
    const long sP = 1024L * 1024;

    prep<<<4966, blk, 0, stream>>>(image, a_qw, a_qb, b_kw, b_kb, b_vw,
                                   a_ow, b_ow, imgT, ctxT, W, qkb, sums);
    // Dispatch 2 (merged): QK[l][co2] (Q_a|K_b, 512 blocks) + vb[co][l] (256)
    {
        GOp opQ = {imgT, Wqk, QK, sIT, 0, sQK, 256, 768, 512, 4, 8, 16, 768,
                   nullptr, qkb, nullptr, nullptr, 0};
        GOp opV = {Wvb, imgT, vb, 0, sIT, sV, 768, 256, 1024, 8, 2, 16, 768,
                   b_vb, nullptr, nullptr, nullptr, 0};
        gemm_nt<<<768, blk, 0, stream>>>(opQ, opV, 512, 1.f);
    }
    // Dispatch 3: rank-4 mats A,d (branch a) and Y,c (branch b) -- grid 1024
    mats<<<1024, blk, 0, stream>>>(QK, a_kw, a_kb, b_qw, b_qb, M4A, M4Y);
    // Dispatch 4: branch-a streaming attention -> ctxT[0..16); branch-b P gen
    attn_mid<<<1280, blk, 0, stream>>>(clinical, M4A, M4Y, a_vw, a_vb,
                                       P, invl, ctxT);
    // Dispatch 5: o-conv-a (-> Y bf16 + BN stats)  ||  PV_b (-> ctxT[16..32))
    {
        GOp opA = {Woa, ctxT, Y, 0, sIT, sV, 768, 256, 1024, 8, 2, 16, 768,
                   a_ob, nullptr, nullptr, sums, 0};
        GOp opPV = {P, vb, ctxT + 16 * sIT + 256, sP, sV, sIT, 1024, 1024, 256,
                    2, 8, 16, 1024, nullptr, nullptr, invl, nullptr, 0};
        gemm_nt<<<512, blk, 0, stream>>>(opA, opPV, 256, 1.f);
    }
    // Dispatch 6: o-conv-b -> Y bf16 + BN stats
    {
        GOp opB = {Wob, ctxT + 16 * sIT, Y + 16 * sV, 0, sIT, sV, 768, 256, 1024,
                   8, 2, 16, 768, b_ob, nullptr, nullptr, sums, 256};
        gemm_nt<<<256, blk, 0, stream>>>(opB, opB, 256, 1.f);
    }
    // BN finalize + apply
    bn_finalize<<<2, blk, 0, stream>>>(sums, a_g, a_be, b_g, b_be, ss);
    bn_apply<<<8192, blk, 0, stream>>>(Y, image, ss, out);
}